// Round 1
// baseline (278.860 us; speedup 1.0000x reference)
//
#include <hip/hip_runtime.h>
#include <math.h>

#define NPATCH 196

__device__ __forceinline__ float sigm(float x)      { return 1.0f / (1.0f + __expf(-x)); }
__device__ __forceinline__ float tanh_fast(float x) { return 1.0f - 2.0f / (1.0f + __expf(2.0f * x)); }

// ---------------------------------------------------------------------------
// Kernel 1: quanv — per (sample b, patch t): simulate 4-qubit REAL statevector
// (initial RY-product state, then per wire w: RY(rl[w]) on w, CNOT(w,(w+1)%4)),
// then measure <Z_w>. Wire w occupies state-index bit (3-w) (wire 0 = MSB).
// Output layout qfeat[t][b][4] so the LSTM kernel reads coalesced per step.
// ---------------------------------------------------------------------------
__global__ __launch_bounds__(256) void quanv_kernel(const float* __restrict__ x,
                                                    const float* __restrict__ rl,
                                                    float* __restrict__ qfeat, int B)
{
    int b = blockIdx.x * blockDim.x + threadIdx.x;
    int t = blockIdx.y;
    if (b >= B) return;
    int i = t / 14, j = t - i * 14;
    // patch pixels: (2i,2j),(2i,2j+1),(2i+1,2j),(2i+1,2j+1)
    const float* row = x + (size_t)b * 784 + i * 56 + j * 2;
    float2 p01 = *(const float2*)(row);
    float2 p23 = *(const float2*)(row + 28);
    float a[4] = {p01.x, p01.y, p23.x, p23.y};

    float cw[4], sw[4];
#pragma unroll
    for (int w = 0; w < 4; ++w) __sincosf(a[w] * 0.5f, &sw[w], &cw[w]);

    float amp[16];
#pragma unroll
    for (int idx = 0; idx < 16; ++idx) {
        float v = ((idx & 8) ? sw[0] : cw[0]) * ((idx & 4) ? sw[1] : cw[1]);
        v *= ((idx & 2) ? sw[2] : cw[2]);
        v *= ((idx & 1) ? sw[3] : cw[3]);
        amp[idx] = v;
    }

#pragma unroll
    for (int w = 0; w < 4; ++w) {
        float sn, ct;
        __sincosf(rl[w] * 0.5f, &sn, &ct);
        const int mask = 8 >> w;
        // RY(rl[w]) on wire w:  new0 = ct*a0 - sn*a1 ; new1 = sn*a0 + ct*a1
#pragma unroll
        for (int idx = 0; idx < 16; ++idx) {
            if (!(idx & mask)) {
                float a0 = amp[idx], a1 = amp[idx | mask];
                amp[idx]        = ct * a0 - sn * a1;
                amp[idx | mask] = sn * a0 + ct * a1;
            }
        }
        const int tmask = 8 >> ((w + 1) & 3);
        // CNOT(w, w+1): for control=1, target=0 swap with target=1
#pragma unroll
        for (int idx = 0; idx < 16; ++idx) {
            if ((idx & mask) && !(idx & tmask)) {
                float tmp = amp[idx];
                amp[idx] = amp[idx | tmask];
                amp[idx | tmask] = tmp;
            }
        }
    }

    float p[16];
#pragma unroll
    for (int idx = 0; idx < 16; ++idx) p[idx] = amp[idx] * amp[idx];
    float z0 = 0.f, z1 = 0.f, z2 = 0.f, z3 = 0.f;
#pragma unroll
    for (int idx = 0; idx < 16; ++idx) {
        z0 += (idx & 8) ? -p[idx] : p[idx];
        z1 += (idx & 4) ? -p[idx] : p[idx];
        z2 += (idx & 2) ? -p[idx] : p[idx];
        z3 += (idx & 1) ? -p[idx] : p[idx];
    }
    *(float4*)(qfeat + ((size_t)t * B + b) * 4) = make_float4(z0, z1, z2, z3);
}

// ---------------------------------------------------------------------------
// Kernel 2: LSTM scan. 4 lanes per sample (lane = hidden unit u).
// qlayer closed form: CNOT chain is a GF(2)-linear basis permutation of a
// product state, so  z0=c1c2c3, z1=c0c1, z2=c0c1c2, z3=c0c1c2c3  with
// c_u = cos((comb@W[k])_u + lin_b[k][u] + qtheta[k][u]).
// Cross-unit products via quad shfl_xor prefix trick. Final h summed over
// batch via wave reduce + atomics into zeroed ws sums[4].
// ---------------------------------------------------------------------------
__global__ __launch_bounds__(256) void lstm_kernel(const float* __restrict__ qfeat,
                                                   const float* __restrict__ lin_W,
                                                   const float* __restrict__ lin_b,
                                                   const float* __restrict__ qtheta,
                                                   float* __restrict__ sums, int B)
{
    int gid = blockIdx.x * blockDim.x + threadIdx.x;
    int smp = gid >> 2;
    int u   = gid & 3;

    float W[4][8], bt[4];
#pragma unroll
    for (int k = 0; k < 4; ++k) {
#pragma unroll
        for (int j = 0; j < 8; ++j) W[k][j] = lin_W[(k * 8 + j) * 4 + u];
        bt[k] = lin_b[k * 4 + u] + qtheta[k * 4 + u];
    }

    float cx = 0.f, hx = 0.f;
    for (int t = 0; t < NPATCH; ++t) {
        float4 xt = *(const float4*)(qfeat + ((size_t)t * B + smp) * 4);
        float h0 = __shfl(hx, 0, 4);
        float h1 = __shfl(hx, 1, 4);
        float h2 = __shfl(hx, 2, 4);
        float h3 = __shfl(hx, 3, 4);

        float z[4];
#pragma unroll
        for (int k = 0; k < 4; ++k) {
            float a2 = bt[k];
            a2 = fmaf(xt.x, W[k][0], a2);
            a2 = fmaf(xt.y, W[k][1], a2);
            a2 = fmaf(xt.z, W[k][2], a2);
            a2 = fmaf(xt.w, W[k][3], a2);
            a2 = fmaf(h0, W[k][4], a2);
            a2 = fmaf(h1, W[k][5], a2);
            a2 = fmaf(h2, W[k][6], a2);
            a2 = fmaf(h3, W[k][7], a2);
            float cv = __cosf(a2);
            float s1 = __shfl_xor(cv, 1, 4);   // c_{u^1}
            float m1 = cv * s1;                // lanes {0,1}: c0c1 ; {2,3}: c2c3
            float s2 = __shfl_xor(m1, 2, 4);   // lanes {0,1}: c2c3 ; {2,3}: c0c1
            float zz = (u == 0) ? s1 * s2      // c1*c2c3
                     : (u == 1) ? m1           // c0c1
                     : (u == 2) ? cv * s2      // c2*c0c1
                                : m1 * s2;     // c0c1c2c3
            z[k] = zz;
        }
        float f  = sigm(z[0]);
        float ii = sigm(z[1]);
        float g  = tanh_fast(z[2]);
        float o  = sigm(z[3]);
        cx = fmaf(f, cx, ii * g);
        hx = o * tanh_fast(cx);
    }

    // sum hx over the 16 samples in this wave (lanes with same u are stride 4)
    float v = hx;
#pragma unroll
    for (int m = 4; m < 64; m <<= 1) v += __shfl_xor(v, m, 64);
    if ((threadIdx.x & 63) < 4) atomicAdd(sums + u, v);
}

// ---------------------------------------------------------------------------
// Kernel 3: out[b] = prod_j cos(w_j) * prod_j cos(x[b][j]), w = sums/B
// ---------------------------------------------------------------------------
__global__ __launch_bounds__(256) void final_kernel(const float* __restrict__ x,
                                                    const float* __restrict__ sums,
                                                    float* __restrict__ out,
                                                    int B, float invB)
{
    int b = blockIdx.x * blockDim.x + threadIdx.x;
    if (b >= B) return;
    float P = cosf(sums[0] * invB) * cosf(sums[1] * invB) *
              cosf(sums[2] * invB) * cosf(sums[3] * invB);
    const float4 xi = *(const float4*)(x + (size_t)b * 784);
    out[b] = P * cosf(xi.x) * cosf(xi.y) * cosf(xi.z) * cosf(xi.w);
}

extern "C" void kernel_launch(void* const* d_in, const int* in_sizes, int n_in,
                              void* d_out, int out_size, void* d_ws, size_t ws_size,
                              hipStream_t stream)
{
    const float* x      = (const float*)d_in[0];
    const float* rl     = (const float*)d_in[1];
    const float* lin_W  = (const float*)d_in[2];
    const float* lin_b  = (const float*)d_in[3];
    const float* qtheta = (const float*)d_in[4];
    float* out = (float*)d_out;
    int B = in_sizes[0] / 784;

    float* sums  = (float*)d_ws;                       // 4 floats
    float* qfeat = (float*)((char*)d_ws + 256);        // [196][B][4] f32

    hipMemsetAsync(sums, 0, 4 * sizeof(float), stream);

    dim3 g1((B + 255) / 256, NPATCH);
    quanv_kernel<<<g1, 256, 0, stream>>>(x, rl, qfeat, B);

    int threads2 = B * 4;
    lstm_kernel<<<(threads2 + 255) / 256, 256, 0, stream>>>(qfeat, lin_W, lin_b, qtheta, sums, B);

    final_kernel<<<(B + 255) / 256, 256, 0, stream>>>(x, sums, out, B, 1.0f / (float)B);
}

// Round 3
// 183.673 us; speedup vs baseline: 1.5182x; 1.5182x over previous
//
#include <hip/hip_runtime.h>
#include <math.h>

#define NPATCH 196

// ---- fast math helpers: native exp2-based exp, raw v_rcp ----
__device__ __forceinline__ float fast_rcp(float x) { return __builtin_amdgcn_rcpf(x); }
__device__ __forceinline__ float sigm(float x)      { return fast_rcp(1.0f + __expf(-x)); }
__device__ __forceinline__ float tanh_fast(float x) { return fmaf(-2.0f, fast_rcp(1.0f + __expf(2.0f * x)), 1.0f); }

// ---- DPP quad-perm: cross-lane within groups of 4 at VALU latency ----
template<int CTRL>
__device__ __forceinline__ float qperm(float x) {
    int i = __float_as_int(x);
    int r = __builtin_amdgcn_update_dpp(i, i, CTRL, 0xF, 0xF, true);
    return __int_as_float(r);
}
// quad_perm encodings: sel0 | sel1<<2 | sel2<<4 | sel3<<6
#define QP_BCAST0 0x00
#define QP_BCAST1 0x55
#define QP_BCAST2 0xAA
#define QP_BCAST3 0xFF
#define QP_XOR1   0xB1   // (1,0,3,2)
#define QP_XOR2   0x4E   // (2,3,0,1)

// ---------------------------------------------------------------------------
// Kernel 1: quanv. Thread = (sample b, patch-row i). Computes 14 patches.
// Wire w occupies state-index bit (3-w). Writes qfeat[t][b][4] — lanes are
// consecutive b -> fully coalesced 1KB/wave stores.
// ---------------------------------------------------------------------------
__global__ __launch_bounds__(256) void quanv_kernel(const float* __restrict__ x,
                                                    const float* __restrict__ rl,
                                                    float* __restrict__ qfeat, int B)
{
    int tid = blockIdx.x * blockDim.x + threadIdx.x;   // 14*B threads
    int b = tid & (B - 1);
    int i = tid >> 13;                                  // B = 8192
    if (i >= 14) return;

    // hoisted per-wire RY rotation
    float rs[4], rc[4];
#pragma unroll
    for (int w = 0; w < 4; ++w) __sincosf(rl[w] * 0.5f, &rs[w], &rc[w]);

    const float* row = x + (size_t)b * 784 + i * 56;

    for (int j = 0; j < 14; ++j) {
        float2 p01 = *(const float2*)(row + j * 2);
        float2 p23 = *(const float2*)(row + j * 2 + 28);
        float a[4] = {p01.x, p01.y, p23.x, p23.y};

        float cw[4], sw[4];
#pragma unroll
        for (int w = 0; w < 4; ++w) __sincosf(a[w] * 0.5f, &sw[w], &cw[w]);

        float amp[16];
#pragma unroll
        for (int idx = 0; idx < 16; ++idx) {
            float v = ((idx & 8) ? sw[0] : cw[0]) * ((idx & 4) ? sw[1] : cw[1]);
            v *= ((idx & 2) ? sw[2] : cw[2]);
            v *= ((idx & 1) ? sw[3] : cw[3]);
            amp[idx] = v;
        }

#pragma unroll
        for (int w = 0; w < 4; ++w) {
            const int mask = 8 >> w;
#pragma unroll
            for (int idx = 0; idx < 16; ++idx) {
                if (!(idx & mask)) {
                    float a0 = amp[idx], a1 = amp[idx | mask];
                    amp[idx]        = rc[w] * a0 - rs[w] * a1;
                    amp[idx | mask] = rs[w] * a0 + rc[w] * a1;
                }
            }
            const int tmask = 8 >> ((w + 1) & 3);
#pragma unroll
            for (int idx = 0; idx < 16; ++idx) {
                if ((idx & mask) && !(idx & tmask)) {
                    float tmp = amp[idx];
                    amp[idx] = amp[idx | tmask];
                    amp[idx | tmask] = tmp;
                }
            }
        }

        float p[16];
#pragma unroll
        for (int idx = 0; idx < 16; ++idx) p[idx] = amp[idx] * amp[idx];
        float z0 = 0.f, z1 = 0.f, z2 = 0.f, z3 = 0.f;
#pragma unroll
        for (int idx = 0; idx < 16; ++idx) {
            z0 += (idx & 8) ? -p[idx] : p[idx];
            z1 += (idx & 4) ? -p[idx] : p[idx];
            z2 += (idx & 2) ? -p[idx] : p[idx];
            z3 += (idx & 1) ? -p[idx] : p[idx];
        }
        int t = i * 14 + j;
        *(float4*)(qfeat + ((size_t)t * B + b) * 4) = make_float4(z0, z1, z2, z3);
    }
}

// ---------------------------------------------------------------------------
// Kernel 2: LSTM scan. 4 lanes per sample (lane = hidden unit u).
// qlayer closed form: z0=c1c2c3, z1=c0c1, z2=c0c1c2, z3=c0c1c2c3 with
// c_u = cos((comb@W[k])_u + lin_b[k][u] + qtheta[k][u]).
// All cross-lane traffic via DPP quad_perm (VALU latency, no LDS).
// qfeat loads software-pipelined 2 deep.
// ---------------------------------------------------------------------------
__global__ __launch_bounds__(256) void lstm_kernel(const float* __restrict__ qfeat,
                                                   const float* __restrict__ lin_W,
                                                   const float* __restrict__ lin_b,
                                                   const float* __restrict__ qtheta,
                                                   float* __restrict__ sums, int B)
{
    int gid = blockIdx.x * blockDim.x + threadIdx.x;
    int smp = gid >> 2;
    int u   = gid & 3;

    float W[4][8], bt[4];
#pragma unroll
    for (int k = 0; k < 4; ++k) {
#pragma unroll
        for (int j = 0; j < 8; ++j) W[k][j] = lin_W[(k * 8 + j) * 4 + u];
        bt[k] = lin_b[k * 4 + u] + qtheta[k * 4 + u];
    }

    const float4* qf = (const float4*)qfeat;
    float4 cur = qf[smp];
    float4 nxt = qf[(size_t)B + smp];

    float cx = 0.f, hx = 0.f;
    for (int t = 0; t < NPATCH; ++t) {
        float4 xt = cur;
        cur = nxt;
        int tn = t + 2;
        if (tn < NPATCH) nxt = qf[(size_t)tn * B + smp];

        float h0 = qperm<QP_BCAST0>(hx);
        float h1 = qperm<QP_BCAST1>(hx);
        float h2 = qperm<QP_BCAST2>(hx);
        float h3 = qperm<QP_BCAST3>(hx);

        float z[4];
#pragma unroll
        for (int k = 0; k < 4; ++k) {
            // two-chain tree to shorten the dependent fma chain
            float s0 = fmaf(xt.x, W[k][0], bt[k]);
            float s1 = xt.y * W[k][1];
            s0 = fmaf(xt.z, W[k][2], s0);
            s1 = fmaf(xt.w, W[k][3], s1);
            s0 = fmaf(h0, W[k][4], s0);
            s1 = fmaf(h1, W[k][5], s1);
            s0 = fmaf(h2, W[k][6], s0);
            s1 = fmaf(h3, W[k][7], s1);
            float cv = __cosf(s0 + s1);
            float sx1 = qperm<QP_XOR1>(cv);    // c_{u^1}
            float m1  = cv * sx1;              // {0,1}: c0c1 ; {2,3}: c2c3
            float sx2 = qperm<QP_XOR2>(m1);    // {0,1}: c2c3 ; {2,3}: c0c1
            float zz = (u == 0) ? sx1 * sx2    // c1*c2c3
                     : (u == 1) ? m1           // c0c1
                     : (u == 2) ? cv * sx2     // c2*c0c1
                                : m1 * sx2;    // c0c1c2c3
            z[k] = zz;
        }
        float f  = sigm(z[0]);
        float ii = sigm(z[1]);
        float g  = tanh_fast(z[2]);
        float o  = sigm(z[3]);
        cx = fmaf(f, cx, ii * g);
        hx = o * tanh_fast(cx);
    }

    // sum hx over the 16 samples in this wave (same-u lanes are stride 4)
    float v = hx;
#pragma unroll
    for (int m = 4; m < 64; m <<= 1) v += __shfl_xor(v, m, 64);
    if ((threadIdx.x & 63) < 4) atomicAdd(sums + u, v);
}

// ---------------------------------------------------------------------------
// Kernel 3: out[b] = prod_j cos(w_j) * prod_j cos(x[b][j]), w = sums/B
// ---------------------------------------------------------------------------
__global__ __launch_bounds__(256) void final_kernel(const float* __restrict__ x,
                                                    const float* __restrict__ sums,
                                                    float* __restrict__ out,
                                                    int B, float invB)
{
    int b = blockIdx.x * blockDim.x + threadIdx.x;
    if (b >= B) return;
    float P = cosf(sums[0] * invB) * cosf(sums[1] * invB) *
              cosf(sums[2] * invB) * cosf(sums[3] * invB);
    const float4 xi = *(const float4*)(x + (size_t)b * 784);
    out[b] = P * cosf(xi.x) * cosf(xi.y) * cosf(xi.z) * cosf(xi.w);
}

extern "C" void kernel_launch(void* const* d_in, const int* in_sizes, int n_in,
                              void* d_out, int out_size, void* d_ws, size_t ws_size,
                              hipStream_t stream)
{
    const float* x      = (const float*)d_in[0];
    const float* rl     = (const float*)d_in[1];
    const float* lin_W  = (const float*)d_in[2];
    const float* lin_b  = (const float*)d_in[3];
    const float* qtheta = (const float*)d_in[4];
    float* out = (float*)d_out;
    int B = in_sizes[0] / 784;

    float* sums  = (float*)d_ws;                       // 4 floats
    float* qfeat = (float*)((char*)d_ws + 256);        // [196][B][4] f32

    hipMemsetAsync(sums, 0, 4 * sizeof(float), stream);

    int threads1 = 14 * B;
    quanv_kernel<<<(threads1 + 255) / 256, 256, 0, stream>>>(x, rl, qfeat, B);

    int threads2 = B * 4;
    lstm_kernel<<<(threads2 + 255) / 256, 256, 0, stream>>>(qfeat, lin_W, lin_b, qtheta, sums, B);

    final_kernel<<<(B + 255) / 256, 256, 0, stream>>>(x, sums, out, B, 1.0f / (float)B);
}

// Round 4
// 176.208 us; speedup vs baseline: 1.5826x; 1.0424x over previous
//
#include <hip/hip_runtime.h>
#include <math.h>

#define NPATCH 196
#define QROWS  200   // 196 + 4 pad rows so the prefetch ring never goes OOB

typedef unsigned short ushort_t;

// ---- fast math helpers ----
__device__ __forceinline__ float fast_rcp(float x) { return __builtin_amdgcn_rcpf(x); }
__device__ __forceinline__ float sigm(float x)      { return fast_rcp(1.0f + __expf(-x)); }
__device__ __forceinline__ float tanh_fast(float x) { return fmaf(-2.0f, fast_rcp(1.0f + __expf(2.0f * x)), 1.0f); }

// ---- bf16 pack/unpack (RNE) ----
__device__ __forceinline__ ushort_t f2bf(float f) {
    unsigned u = __float_as_uint(f);
    u += 0x7FFFu + ((u >> 16) & 1u);
    return (ushort_t)(u >> 16);
}
__device__ __forceinline__ float bf2f(ushort_t h) { return __uint_as_float((unsigned)h << 16); }

// ---- DPP quad-perm: cross-lane within groups of 4 at VALU latency ----
template<int CTRL>
__device__ __forceinline__ float qperm(float x) {
    int i = __float_as_int(x);
    int r = __builtin_amdgcn_update_dpp(i, i, CTRL, 0xF, 0xF, true);
    return __int_as_float(r);
}
#define QP_BCAST0 0x00
#define QP_BCAST1 0x55
#define QP_BCAST2 0xAA
#define QP_BCAST3 0xFF
#define QP_XOR1   0xB1   // (1,0,3,2)
#define QP_XOR2   0x4E   // (2,3,0,1)

// ---------------------------------------------------------------------------
// Kernel 1: quanv. Block = 16 samples staged in LDS (coalesced float4 loads,
// row pitch 788 floats -> worst 2-way bank conflict = free). Thread (s,tg)
// computes patches t = tg, tg+16, ... via 4-qubit real statevector sim.
// Output qfeat[t][b] as bf16x4 (8B), coalesced across s.
// ---------------------------------------------------------------------------
#define SPB  16
#define ROWP 788

__global__ __launch_bounds__(256) void quanv_kernel(const float* __restrict__ x,
                                                    const float* __restrict__ rl,
                                                    ushort_t* __restrict__ qfeat, int B)
{
    __shared__ float tile[SPB][ROWP];
    const int tid = threadIdx.x;
    const int b0  = blockIdx.x * SPB;

    // coalesced stage: 16 rows x 196 float4 each
#pragma unroll 4
    for (int r = 0; r < SPB; ++r) {
        if (tid < 196) {
            ((float4*)&tile[r][0])[tid] =
                ((const float4*)(x + (size_t)(b0 + r) * 784))[tid];
        }
    }
    __syncthreads();

    float rs[4], rc[4];
#pragma unroll
    for (int w = 0; w < 4; ++w) __sincosf(rl[w] * 0.5f, &rs[w], &rc[w]);

    const int s  = tid & 15;
    const int tg = tid >> 4;                 // 0..15
    const float* row = &tile[s][0];

    for (int t = tg; t < NPATCH; t += 16) {
        int i = t / 14, j = t - i * 14;
        int o = i * 56 + j * 2;
        float a[4] = { row[o], row[o + 1], row[o + 28], row[o + 29] };

        float cw[4], sw[4];
#pragma unroll
        for (int w = 0; w < 4; ++w) __sincosf(a[w] * 0.5f, &sw[w], &cw[w]);

        float amp[16];
#pragma unroll
        for (int idx = 0; idx < 16; ++idx) {
            float v = ((idx & 8) ? sw[0] : cw[0]) * ((idx & 4) ? sw[1] : cw[1]);
            v *= ((idx & 2) ? sw[2] : cw[2]);
            v *= ((idx & 1) ? sw[3] : cw[3]);
            amp[idx] = v;
        }

#pragma unroll
        for (int w = 0; w < 4; ++w) {
            const int mask = 8 >> w;
#pragma unroll
            for (int idx = 0; idx < 16; ++idx) {
                if (!(idx & mask)) {
                    float a0 = amp[idx], a1 = amp[idx | mask];
                    amp[idx]        = rc[w] * a0 - rs[w] * a1;
                    amp[idx | mask] = rs[w] * a0 + rc[w] * a1;
                }
            }
            const int tmask = 8 >> ((w + 1) & 3);
#pragma unroll
            for (int idx = 0; idx < 16; ++idx) {
                if ((idx & mask) && !(idx & tmask)) {
                    float tmp = amp[idx];
                    amp[idx] = amp[idx | tmask];
                    amp[idx | tmask] = tmp;
                }
            }
        }

        float p[16];
#pragma unroll
        for (int idx = 0; idx < 16; ++idx) p[idx] = amp[idx] * amp[idx];
        float z0 = 0.f, z1 = 0.f, z2 = 0.f, z3 = 0.f;
#pragma unroll
        for (int idx = 0; idx < 16; ++idx) {
            z0 += (idx & 8) ? -p[idx] : p[idx];
            z1 += (idx & 4) ? -p[idx] : p[idx];
            z2 += (idx & 2) ? -p[idx] : p[idx];
            z3 += (idx & 1) ? -p[idx] : p[idx];
        }

        ushort4 outv;
        outv.x = f2bf(z0); outv.y = f2bf(z1); outv.z = f2bf(z2); outv.w = f2bf(z3);
        *(ushort4*)(qfeat + ((size_t)t * B + (b0 + s)) * 4) = outv;
    }
}

// ---------------------------------------------------------------------------
// Kernel 2: LSTM scan. 4 lanes per sample (lane = hidden unit u).
// qlayer closed form: z0=c1c2c3, z1=c0c1, z2=c0c1c2, z3=c0c1c2c3 with
// c_u = cos((comb@W[k])_u + lin_b[k][u] + qtheta[k][u]).
// Cross-lane via DPP quad_perm. qfeat (bf16x4) loaded through a depth-4
// register ring, loads issued BEFORE each step's compute (~3.5 steps cover).
// 64-thread blocks -> 512 blocks engage all 256 CUs.
// ---------------------------------------------------------------------------
__global__ __launch_bounds__(64) void lstm_kernel(const ushort_t* __restrict__ qfeat,
                                                  const float* __restrict__ lin_W,
                                                  const float* __restrict__ lin_b,
                                                  const float* __restrict__ qtheta,
                                                  float* __restrict__ sums, int B)
{
    int gid = blockIdx.x * 64 + threadIdx.x;
    int smp = gid >> 2;
    int u   = gid & 3;

    float W[4][8], bt[4];
#pragma unroll
    for (int k = 0; k < 4; ++k) {
#pragma unroll
        for (int j = 0; j < 8; ++j) W[k][j] = lin_W[(k * 8 + j) * 4 + u];
        bt[k] = lin_b[k * 4 + u] + qtheta[k * 4 + u];
    }

    const ushort4* qf = (const ushort4*)qfeat;   // one entry per (t, sample)
    ushort4 r0 = qf[(size_t)0 * B + smp];
    ushort4 r1 = qf[(size_t)1 * B + smp];
    ushort4 r2 = qf[(size_t)2 * B + smp];
    ushort4 r3 = qf[(size_t)3 * B + smp];

    float cx = 0.f, hx = 0.f;

    auto step = [&](ushort4& buf, int tn) {
        float xt0 = bf2f(buf.x), xt1 = bf2f(buf.y), xt2 = bf2f(buf.z), xt3 = bf2f(buf.w);
        buf = qf[(size_t)tn * B + smp];          // prefetch issued before compute

        float h0 = qperm<QP_BCAST0>(hx);
        float h1 = qperm<QP_BCAST1>(hx);
        float h2 = qperm<QP_BCAST2>(hx);
        float h3 = qperm<QP_BCAST3>(hx);

        float z[4];
#pragma unroll
        for (int k = 0; k < 4; ++k) {
            float s0 = fmaf(xt0, W[k][0], bt[k]);
            float s1 = xt1 * W[k][1];
            s0 = fmaf(xt2, W[k][2], s0);
            s1 = fmaf(xt3, W[k][3], s1);
            s0 = fmaf(h0, W[k][4], s0);
            s1 = fmaf(h1, W[k][5], s1);
            s0 = fmaf(h2, W[k][6], s0);
            s1 = fmaf(h3, W[k][7], s1);
            float cv = __cosf(s0 + s1);
            float sx1 = qperm<QP_XOR1>(cv);      // c_{u^1}
            float m1  = cv * sx1;                // {0,1}: c0c1 ; {2,3}: c2c3
            float sx2 = qperm<QP_XOR2>(m1);      // {0,1}: c2c3 ; {2,3}: c0c1
            float zz = (u == 0) ? sx1 * sx2      // c1*c2c3
                     : (u == 1) ? m1             // c0c1
                     : (u == 2) ? cv * sx2       // c2*c0c1
                                : m1 * sx2;      // c0c1c2c3
            z[k] = zz;
        }
        float f  = sigm(z[0]);
        float ii = sigm(z[1]);
        float g  = tanh_fast(z[2]);
        float o  = sigm(z[3]);
        cx = fmaf(f, cx, ii * g);
        hx = o * tanh_fast(cx);
    };

    for (int t = 0; t < NPATCH; t += 4) {
        step(r0, t + 4);
        step(r1, t + 5);
        step(r2, t + 6);
        step(r3, t + 7);   // rows 196..199 exist (pad), loaded but never decoded
    }

    // sum hx over the 16 samples in this wave (same-u lanes are stride 4)
    float v = hx;
#pragma unroll
    for (int m = 4; m < 64; m <<= 1) v += __shfl_xor(v, m, 64);
    if ((threadIdx.x & 63) < 4) atomicAdd(sums + u, v);
}

// ---------------------------------------------------------------------------
// Kernel 3: out[b] = prod_j cos(w_j) * prod_j cos(x[b][j]), w = sums/B
// ---------------------------------------------------------------------------
__global__ __launch_bounds__(256) void final_kernel(const float* __restrict__ x,
                                                    const float* __restrict__ sums,
                                                    float* __restrict__ out,
                                                    int B, float invB)
{
    int b = blockIdx.x * blockDim.x + threadIdx.x;
    if (b >= B) return;
    float P = cosf(sums[0] * invB) * cosf(sums[1] * invB) *
              cosf(sums[2] * invB) * cosf(sums[3] * invB);
    const float4 xi = *(const float4*)(x + (size_t)b * 784);
    out[b] = P * cosf(xi.x) * cosf(xi.y) * cosf(xi.z) * cosf(xi.w);
}

extern "C" void kernel_launch(void* const* d_in, const int* in_sizes, int n_in,
                              void* d_out, int out_size, void* d_ws, size_t ws_size,
                              hipStream_t stream)
{
    const float* x      = (const float*)d_in[0];
    const float* rl     = (const float*)d_in[1];
    const float* lin_W  = (const float*)d_in[2];
    const float* lin_b  = (const float*)d_in[3];
    const float* qtheta = (const float*)d_in[4];
    float* out = (float*)d_out;
    int B = in_sizes[0] / 784;

    float*    sums  = (float*)d_ws;                      // 4 floats
    ushort_t* qfeat = (ushort_t*)((char*)d_ws + 256);    // [QROWS][B][4] bf16

    hipMemsetAsync(sums, 0, 4 * sizeof(float), stream);

    quanv_kernel<<<B / SPB, 256, 0, stream>>>(x, rl, qfeat, B);

    lstm_kernel<<<(B * 4) / 64, 64, 0, stream>>>(qfeat, lin_W, lin_b, qtheta, sums, B);

    final_kernel<<<(B + 255) / 256, 256, 0, stream>>>(x, sums, out, B, 1.0f / (float)B);
}

// Round 5
// 147.974 us; speedup vs baseline: 1.8845x; 1.1908x over previous
//
#include <hip/hip_runtime.h>
#include <math.h>

#define NPATCH 196
#define QROWS  204   // 196 + 8 pad rows so the depth-7 prefetch ring never goes OOB

typedef unsigned short ushort_t;

// ---- fast math helpers ----
__device__ __forceinline__ float fast_rcp(float x) { return __builtin_amdgcn_rcpf(x); }
__device__ __forceinline__ float sigm(float x)      { return fast_rcp(1.0f + __expf(-x)); }
__device__ __forceinline__ float tanh_fast(float x) { return fmaf(-2.0f, fast_rcp(1.0f + __expf(2.0f * x)), 1.0f); }

// ---- bf16 pack/unpack (RNE) ----
__device__ __forceinline__ ushort_t f2bf(float f) {
    unsigned u = __float_as_uint(f);
    u += 0x7FFFu + ((u >> 16) & 1u);
    return (ushort_t)(u >> 16);
}
__device__ __forceinline__ float bf2f(ushort_t h) { return __uint_as_float((unsigned)h << 16); }

// ---- DPP cross-lane (VALU latency, no LDS) ----
template<int CTRL>
__device__ __forceinline__ int dpp_i(int x) {
    return __builtin_amdgcn_update_dpp(x, x, CTRL, 0xF, 0xF, true);
}
template<int CTRL>
__device__ __forceinline__ float dpp_f(float x) {
    return __int_as_float(dpp_i<CTRL>(__float_as_int(x)));
}
#define QP_BCAST0 0x00
#define QP_BCAST1 0x55
#define QP_BCAST2 0xAA
#define QP_BCAST3 0xFF
#define ROR4      0x124   // row_ror:4  (16-lane row rotate; direction probed at runtime)
#define ROR8      0x128
#define ROR12     0x12C

// ---------------------------------------------------------------------------
// Kernel 1: quanv (unchanged from R4 for attribution). Block = 16 samples in
// LDS, thread (s,tg) computes patches t = tg, tg+16, ...; bf16x4 output.
// ---------------------------------------------------------------------------
#define SPB  16
#define ROWP 788

__global__ __launch_bounds__(256) void quanv_kernel(const float* __restrict__ x,
                                                    const float* __restrict__ rl,
                                                    ushort_t* __restrict__ qfeat, int B)
{
    __shared__ float tile[SPB][ROWP];
    const int tid = threadIdx.x;
    const int b0  = blockIdx.x * SPB;

#pragma unroll 4
    for (int r = 0; r < SPB; ++r) {
        if (tid < 196) {
            ((float4*)&tile[r][0])[tid] =
                ((const float4*)(x + (size_t)(b0 + r) * 784))[tid];
        }
    }
    __syncthreads();

    float rs[4], rc[4];
#pragma unroll
    for (int w = 0; w < 4; ++w) __sincosf(rl[w] * 0.5f, &rs[w], &rc[w]);

    const int s  = tid & 15;
    const int tg = tid >> 4;
    const float* row = &tile[s][0];

    for (int t = tg; t < NPATCH; t += 16) {
        int i = t / 14, j = t - i * 14;
        int o = i * 56 + j * 2;
        float a[4] = { row[o], row[o + 1], row[o + 28], row[o + 29] };

        float cw[4], sw[4];
#pragma unroll
        for (int w = 0; w < 4; ++w) __sincosf(a[w] * 0.5f, &sw[w], &cw[w]);

        float amp[16];
#pragma unroll
        for (int idx = 0; idx < 16; ++idx) {
            float v = ((idx & 8) ? sw[0] : cw[0]) * ((idx & 4) ? sw[1] : cw[1]);
            v *= ((idx & 2) ? sw[2] : cw[2]);
            v *= ((idx & 1) ? sw[3] : cw[3]);
            amp[idx] = v;
        }

#pragma unroll
        for (int w = 0; w < 4; ++w) {
            const int mask = 8 >> w;
#pragma unroll
            for (int idx = 0; idx < 16; ++idx) {
                if (!(idx & mask)) {
                    float a0 = amp[idx], a1 = amp[idx | mask];
                    amp[idx]        = rc[w] * a0 - rs[w] * a1;
                    amp[idx | mask] = rs[w] * a0 + rc[w] * a1;
                }
            }
            const int tmask = 8 >> ((w + 1) & 3);
#pragma unroll
            for (int idx = 0; idx < 16; ++idx) {
                if ((idx & mask) && !(idx & tmask)) {
                    float tmp = amp[idx];
                    amp[idx] = amp[idx | tmask];
                    amp[idx | tmask] = tmp;
                }
            }
        }

        float p[16];
#pragma unroll
        for (int idx = 0; idx < 16; ++idx) p[idx] = amp[idx] * amp[idx];
        float z0 = 0.f, z1 = 0.f, z2 = 0.f, z3 = 0.f;
#pragma unroll
        for (int idx = 0; idx < 16; ++idx) {
            z0 += (idx & 8) ? -p[idx] : p[idx];
            z1 += (idx & 4) ? -p[idx] : p[idx];
            z2 += (idx & 2) ? -p[idx] : p[idx];
            z3 += (idx & 1) ? -p[idx] : p[idx];
        }

        ushort4 outv;
        outv.x = f2bf(z0); outv.y = f2bf(z1); outv.z = f2bf(z2); outv.w = f2bf(z3);
        *(ushort4*)(qfeat + ((size_t)t * B + (b0 + s)) * 4) = outv;
    }
}

// ---------------------------------------------------------------------------
// Kernel 2: LSTM scan, 16 lanes per sample: lane16 = u*4 + k (u = unit/wire,
// k = gate circuit). Lane (u,k) computes c_u^{(k)} = cos((comb@W[k])_u + b + th).
//  - h gather across u: row_ror 4/8/12 (absolute source u probed at init).
//  - z[k][u] = masked product of {c_j^{(k)}} over S_u (3 rors + selects).
//  - f,i,g,o collection across k: quad_perm BCAST (quad = fixed u).
// State (cx,hx) replicated across the 4 k-lanes of each quad.
// Ring depth 7 (196 = 7*28) covers HBM latency.
// ---------------------------------------------------------------------------
__global__ __launch_bounds__(256) void lstm_kernel(const ushort_t* __restrict__ qfeat,
                                                   const float* __restrict__ lin_W,
                                                   const float* __restrict__ lin_b,
                                                   const float* __restrict__ qtheta,
                                                   float* __restrict__ sums, int B)
{
    const int tid = threadIdx.x;
    const int gid = blockIdx.x * 256 + tid;
    const int smp = gid >> 4;
    const int u   = (tid >> 2) & 3;
    const int k   = tid & 3;

    // --- direction probe: which absolute u arrives via each ror ---
    const int j1 = dpp_i<ROR4>(u);
    const int j2 = dpp_i<ROR8>(u);
    const int j3 = dpp_i<ROR12>(u);

    // --- per-lane weights: column u of circuit k ---
    float Wx0 = lin_W[(k * 8 + 0) * 4 + u];
    float Wx1 = lin_W[(k * 8 + 1) * 4 + u];
    float Wx2 = lin_W[(k * 8 + 2) * 4 + u];
    float Wx3 = lin_W[(k * 8 + 3) * 4 + u];
    float Wh0 = lin_W[(k * 8 + 4 + u)  * 4 + u];   // pairs with hx  (h_u)
    float Wh1 = lin_W[(k * 8 + 4 + j1) * 4 + u];   // pairs with ror4(hx)
    float Wh2 = lin_W[(k * 8 + 4 + j2) * 4 + u];   // pairs with ror8(hx)
    float Wh3 = lin_W[(k * 8 + 4 + j3) * 4 + u];   // pairs with ror12(hx)
    float bt  = lin_b[k * 4 + u] + qtheta[k * 4 + u];

    // --- product-subset masks: S_0={1,2,3}, S_1={0,1}, S_2={0,1,2}, S_3=all ---
    auto in_set = [](int j, int uu) {
        return (uu == 0) ? (j != 0) : (uu == 1) ? (j <= 1) : (uu == 2) ? (j <= 2) : true;
    };
    const bool inc0 = in_set(u,  u);
    const bool inc1 = in_set(j1, u);
    const bool inc2 = in_set(j2, u);
    const bool inc3 = in_set(j3, u);

    // --- gate nonlinearity constants: k==2 -> tanh, else sigmoid ---
    const float mlt = (k == 2) ?  2.0f : -1.0f;   // exp arg multiplier
    const float ga  = (k == 2) ? -2.0f :  1.0f;   // gv = fma(rcp, ga, gb)
    const float gb  = (k == 2) ?  1.0f :  0.0f;

    const ushort4* qf = (const ushort4*)qfeat;
    ushort4 r0 = qf[(size_t)0 * B + smp];
    ushort4 r1 = qf[(size_t)1 * B + smp];
    ushort4 r2 = qf[(size_t)2 * B + smp];
    ushort4 r3 = qf[(size_t)3 * B + smp];
    ushort4 r4 = qf[(size_t)4 * B + smp];
    ushort4 r5 = qf[(size_t)5 * B + smp];
    ushort4 r6 = qf[(size_t)6 * B + smp];

    float cx = 0.f, hx = 0.f;

    auto step = [&](ushort4& buf, int tn) {
        float xt0 = bf2f(buf.x), xt1 = bf2f(buf.y), xt2 = bf2f(buf.z), xt3 = bf2f(buf.w);
        buf = qf[(size_t)tn * B + smp];              // prefetch 7 steps ahead

        float hr1 = dpp_f<ROR4>(hx);                 // h_{j1}
        float hr2 = dpp_f<ROR8>(hx);                 // h_{j2}
        float hr3 = dpp_f<ROR12>(hx);                // h_{j3}

        float s0 = fmaf(xt0, Wx0, bt);
        float s1 = xt1 * Wx1;
        s0 = fmaf(xt2, Wx2, s0);
        s1 = fmaf(xt3, Wx3, s1);
        s0 = fmaf(hx,  Wh0, s0);
        s1 = fmaf(hr1, Wh1, s1);
        s0 = fmaf(hr2, Wh2, s0);
        s1 = fmaf(hr3, Wh3, s1);
        float cv = __cosf(s0 + s1);                  // c_u^{(k)}

        float c1 = dpp_f<ROR4>(cv);                  // c_{j1}^{(k)}
        float c2 = dpp_f<ROR8>(cv);
        float c3 = dpp_f<ROR12>(cv);
        float t0 = inc0 ? cv : 1.0f;
        float t1 = inc1 ? c1 : 1.0f;
        float t2 = inc2 ? c2 : 1.0f;
        float t3 = inc3 ? c3 : 1.0f;
        float z  = (t0 * t1) * (t2 * t3);            // z[k][u]

        float e  = __expf(z * mlt);
        float gv = fmaf(fast_rcp(1.0f + e), ga, gb); // gate_k[u]

        float f  = dpp_f<QP_BCAST0>(gv);             // f[u]  (k=0 lane of quad)
        float ii = dpp_f<QP_BCAST1>(gv);             // i[u]
        float gg = dpp_f<QP_BCAST2>(gv);             // g[u]
        float o  = dpp_f<QP_BCAST3>(gv);             // o[u]

        cx = fmaf(f, cx, ii * gg);
        hx = o * tanh_fast(cx);
    };

    for (int t = 0; t < NPATCH; t += 7) {
        step(r0, t + 7);
        step(r1, t + 8);
        step(r2, t + 9);
        step(r3, t + 10);
        step(r4, t + 11);
        step(r5, t + 12);
        step(r6, t + 13);
    }

    // batch-sum of final h: reduce the 4 row-samples of this wave, then one
    // atomic per (wave, u) from the k==0 lane of row 0.
    float v = hx;
    v += __shfl_xor(v, 16, 64);
    v += __shfl_xor(v, 32, 64);
    if ((tid & 63) < 16 && k == 0) atomicAdd(sums + u, v);
}

// ---------------------------------------------------------------------------
// Kernel 3: out[b] = prod_j cos(w_j) * prod_j cos(x[b][j]), w = sums/B
// ---------------------------------------------------------------------------
__global__ __launch_bounds__(256) void final_kernel(const float* __restrict__ x,
                                                    const float* __restrict__ sums,
                                                    float* __restrict__ out,
                                                    int B, float invB)
{
    int b = blockIdx.x * blockDim.x + threadIdx.x;
    if (b >= B) return;
    float P = cosf(sums[0] * invB) * cosf(sums[1] * invB) *
              cosf(sums[2] * invB) * cosf(sums[3] * invB);
    const float4 xi = *(const float4*)(x + (size_t)b * 784);
    out[b] = P * cosf(xi.x) * cosf(xi.y) * cosf(xi.z) * cosf(xi.w);
}

extern "C" void kernel_launch(void* const* d_in, const int* in_sizes, int n_in,
                              void* d_out, int out_size, void* d_ws, size_t ws_size,
                              hipStream_t stream)
{
    const float* x      = (const float*)d_in[0];
    const float* rl     = (const float*)d_in[1];
    const float* lin_W  = (const float*)d_in[2];
    const float* lin_b  = (const float*)d_in[3];
    const float* qtheta = (const float*)d_in[4];
    float* out = (float*)d_out;
    int B = in_sizes[0] / 784;

    float*    sums  = (float*)d_ws;                      // 4 floats
    ushort_t* qfeat = (ushort_t*)((char*)d_ws + 256);    // [QROWS][B][4] bf16

    hipMemsetAsync(sums, 0, 4 * sizeof(float), stream);

    quanv_kernel<<<B / SPB, 256, 0, stream>>>(x, rl, qfeat, B);

    lstm_kernel<<<(B * 16) / 256, 256, 0, stream>>>(qfeat, lin_W, lin_b, qtheta, sums, B);

    final_kernel<<<(B + 255) / 256, 256, 0, stream>>>(x, sums, out, B, 1.0f / (float)B);
}

// Round 8
// 146.657 us; speedup vs baseline: 1.9014x; 1.0090x over previous
//
#include <hip/hip_runtime.h>
#include <math.h>

#define NPATCH 196
#define QROWS  204   // 196 + 8 pad rows so the depth-7 prefetch ring never goes OOB

typedef unsigned short ushort_t;

// ---- fast math helpers ----
__device__ __forceinline__ float fast_rcp(float x) { return __builtin_amdgcn_rcpf(x); }

// ---- bf16 pack/unpack ----
__device__ __forceinline__ ushort_t f2bf(float f) {
    unsigned u = __float_as_uint(f);
    u += 0x7FFFu + ((u >> 16) & 1u);
    return (ushort_t)(u >> 16);
}
__device__ __forceinline__ float bflo(unsigned v) { return __uint_as_float(v << 16); }          // low bf16 of dword
__device__ __forceinline__ float bfhi(unsigned v) { return __uint_as_float(v & 0xFFFF0000u); }  // high bf16 of dword

// ---- DPP cross-lane (VALU latency, no LDS) ----
template<int CTRL>
__device__ __forceinline__ int dpp_i(int x) {
    return __builtin_amdgcn_update_dpp(x, x, CTRL, 0xF, 0xF, true);
}
template<int CTRL>
__device__ __forceinline__ float dpp_f(float x) {
    return __int_as_float(dpp_i<CTRL>(__float_as_int(x)));
}
#define QP_BCAST0 0x00
#define QP_BCAST1 0x55
#define QP_BCAST2 0xAA
#define QP_BCAST3 0xFF
#define ROR4      0x124   // row_ror:4 (16-lane row rotate; absolute source probed at runtime)
#define ROR8      0x128
#define ROR12     0x12C

// ---------------------------------------------------------------------------
// Kernel 1: quanv (unchanged from R4/R5 for attribution). Block = 16 samples
// in LDS, thread (s,tg) computes patches t = tg, tg+16, ...; bf16x4 output.
// ---------------------------------------------------------------------------
#define SPB  16
#define ROWP 788

__global__ __launch_bounds__(256) void quanv_kernel(const float* __restrict__ x,
                                                    const float* __restrict__ rl,
                                                    ushort_t* __restrict__ qfeat, int B)
{
    __shared__ float tile[SPB][ROWP];
    const int tid = threadIdx.x;
    const int b0  = blockIdx.x * SPB;

#pragma unroll 4
    for (int r = 0; r < SPB; ++r) {
        if (tid < 196) {
            ((float4*)&tile[r][0])[tid] =
                ((const float4*)(x + (size_t)(b0 + r) * 784))[tid];
        }
    }
    __syncthreads();

    float rs[4], rc[4];
#pragma unroll
    for (int w = 0; w < 4; ++w) __sincosf(rl[w] * 0.5f, &rs[w], &rc[w]);

    const int s  = tid & 15;
    const int tg = tid >> 4;
    const float* row = &tile[s][0];

    for (int t = tg; t < NPATCH; t += 16) {
        int i = t / 14, j = t - i * 14;
        int o = i * 56 + j * 2;
        float a[4] = { row[o], row[o + 1], row[o + 28], row[o + 29] };

        float cw[4], sw[4];
#pragma unroll
        for (int w = 0; w < 4; ++w) __sincosf(a[w] * 0.5f, &sw[w], &cw[w]);

        float amp[16];
#pragma unroll
        for (int idx = 0; idx < 16; ++idx) {
            float v = ((idx & 8) ? sw[0] : cw[0]) * ((idx & 4) ? sw[1] : cw[1]);
            v *= ((idx & 2) ? sw[2] : cw[2]);
            v *= ((idx & 1) ? sw[3] : cw[3]);
            amp[idx] = v;
        }

#pragma unroll
        for (int w = 0; w < 4; ++w) {
            const int mask = 8 >> w;
#pragma unroll
            for (int idx = 0; idx < 16; ++idx) {
                if (!(idx & mask)) {
                    float a0 = amp[idx], a1 = amp[idx | mask];
                    amp[idx]        = rc[w] * a0 - rs[w] * a1;
                    amp[idx | mask] = rs[w] * a0 + rc[w] * a1;
                }
            }
            const int tmask = 8 >> ((w + 1) & 3);
#pragma unroll
            for (int idx = 0; idx < 16; ++idx) {
                if ((idx & mask) && !(idx & tmask)) {
                    float tmp = amp[idx];
                    amp[idx] = amp[idx | tmask];
                    amp[idx | tmask] = tmp;
                }
            }
        }

        float p[16];
#pragma unroll
        for (int idx = 0; idx < 16; ++idx) p[idx] = amp[idx] * amp[idx];
        float z0 = 0.f, z1 = 0.f, z2 = 0.f, z3 = 0.f;
#pragma unroll
        for (int idx = 0; idx < 16; ++idx) {
            z0 += (idx & 8) ? -p[idx] : p[idx];
            z1 += (idx & 4) ? -p[idx] : p[idx];
            z2 += (idx & 2) ? -p[idx] : p[idx];
            z3 += (idx & 1) ? -p[idx] : p[idx];
        }

        ushort4 outv;
        outv.x = f2bf(z0); outv.y = f2bf(z1); outv.z = f2bf(z2); outv.w = f2bf(z3);
        *(ushort4*)(qfeat + ((size_t)t * B + (b0 + s)) * 4) = outv;
    }
}

// ---------------------------------------------------------------------------
// Kernel 2: LSTM scan, 16 lanes per SAMPLE-PAIR: lane16 = u*4 + k; each
// thread runs two independent samples (A = 2*pr, B = 2*pr+1) so one wave
// carries two dependency chains (ILP replaces the missing TLP).
// One dwordx4 load per step feeds both samples (adjacent in qfeat).
// Ring depth 7 (196 = 7*28) covers HBM latency.
// ---------------------------------------------------------------------------
__global__ __launch_bounds__(256) void lstm_kernel(const ushort_t* __restrict__ qfeat,
                                                   const float* __restrict__ lin_W,
                                                   const float* __restrict__ lin_b,
                                                   const float* __restrict__ qtheta,
                                                   float* __restrict__ sums, int B)
{
    const int tid = threadIdx.x;
    const int gid = blockIdx.x * 256 + tid;
    const int pr  = gid >> 4;           // sample-pair index, 0 .. B/2-1
    const int u   = (tid >> 2) & 3;
    const int k   = tid & 3;
    const int Bh  = B >> 1;

    // --- direction probe: which absolute u arrives via each ror ---
    const int j1 = dpp_i<ROR4>(u);
    const int j2 = dpp_i<ROR8>(u);
    const int j3 = dpp_i<ROR12>(u);

    // --- per-lane weights: column u of circuit k ---
    const float Wx0 = lin_W[(k * 8 + 0) * 4 + u];
    const float Wx1 = lin_W[(k * 8 + 1) * 4 + u];
    const float Wx2 = lin_W[(k * 8 + 2) * 4 + u];
    const float Wx3 = lin_W[(k * 8 + 3) * 4 + u];
    const float Wh0 = lin_W[(k * 8 + 4 + u)  * 4 + u];
    const float Wh1 = lin_W[(k * 8 + 4 + j1) * 4 + u];
    const float Wh2 = lin_W[(k * 8 + 4 + j2) * 4 + u];
    const float Wh3 = lin_W[(k * 8 + 4 + j3) * 4 + u];
    const float bt  = lin_b[k * 4 + u] + qtheta[k * 4 + u];

    // --- product-subset masks: S_0={1,2,3}, S_1={0,1}, S_2={0,1,2}, S_3=all ---
    auto in_set = [](int j, int uu) {
        return (uu == 0) ? (j != 0) : (uu == 1) ? (j <= 1) : (uu == 2) ? (j <= 2) : true;
    };
    const bool inc0 = in_set(u,  u);
    const bool inc1 = in_set(j1, u);
    const bool inc2 = in_set(j2, u);
    const bool inc3 = in_set(j3, u);

    // --- gate nonlinearity constants: k==2 -> tanh, else sigmoid ---
    const float mlt = (k == 2) ?  2.0f : -1.0f;
    const float ga  = (k == 2) ? -2.0f :  1.0f;
    const float gb  = (k == 2) ?  1.0f :  0.0f;

    const uint4* qp = (const uint4*)qfeat;    // 16 B = one t, one sample pair
    uint4 r0 = qp[(size_t)0 * Bh + pr];
    uint4 r1 = qp[(size_t)1 * Bh + pr];
    uint4 r2 = qp[(size_t)2 * Bh + pr];
    uint4 r3 = qp[(size_t)3 * Bh + pr];
    uint4 r4 = qp[(size_t)4 * Bh + pr];
    uint4 r5 = qp[(size_t)5 * Bh + pr];
    uint4 r6 = qp[(size_t)6 * Bh + pr];

    float cxa = 0.f, hxa = 0.f;   // sample A = 2*pr
    float cxb = 0.f, hxb = 0.f;   // sample B = 2*pr+1

    auto step = [&](uint4& buf, int tn) {
        // decode both samples (A: dwords x,y ; B: dwords z,w)
        float ax0 = bflo(buf.x), ax1 = bfhi(buf.x), ax2 = bflo(buf.y), ax3 = bfhi(buf.y);
        float bx0 = bflo(buf.z), bx1 = bfhi(buf.z), bx2 = bflo(buf.w), bx3 = bfhi(buf.w);
        buf = qp[(size_t)tn * Bh + pr];          // prefetch 7 steps ahead

        // h gathers (independent chains A and B interleave in the scheduler)
        float ha1 = dpp_f<ROR4>(hxa), hb1 = dpp_f<ROR4>(hxb);
        float ha2 = dpp_f<ROR8>(hxa), hb2 = dpp_f<ROR8>(hxb);
        float ha3 = dpp_f<ROR12>(hxa), hb3 = dpp_f<ROR12>(hxb);

        float as0 = fmaf(ax0, Wx0, bt);
        float bs0 = fmaf(bx0, Wx0, bt);
        float as1 = ax1 * Wx1;
        float bs1 = bx1 * Wx1;
        as0 = fmaf(ax2, Wx2, as0);  bs0 = fmaf(bx2, Wx2, bs0);
        as1 = fmaf(ax3, Wx3, as1);  bs1 = fmaf(bx3, Wx3, bs1);
        as0 = fmaf(hxa, Wh0, as0);  bs0 = fmaf(hxb, Wh0, bs0);
        as1 = fmaf(ha1, Wh1, as1);  bs1 = fmaf(hb1, Wh1, bs1);
        as0 = fmaf(ha2, Wh2, as0);  bs0 = fmaf(hb2, Wh2, bs0);
        as1 = fmaf(ha3, Wh3, as1);  bs1 = fmaf(hb3, Wh3, bs1);
        float cva = __cosf(as0 + as1);
        float cvb = __cosf(bs0 + bs1);

        float ca1 = dpp_f<ROR4>(cva),  cb1 = dpp_f<ROR4>(cvb);
        float ca2 = dpp_f<ROR8>(cva),  cb2 = dpp_f<ROR8>(cvb);
        float ca3 = dpp_f<ROR12>(cva), cb3 = dpp_f<ROR12>(cvb);
        float za = (inc0 ? cva : 1.0f) * (inc1 ? ca1 : 1.0f)
                 * ((inc2 ? ca2 : 1.0f) * (inc3 ? ca3 : 1.0f));
        float zb = (inc0 ? cvb : 1.0f) * (inc1 ? cb1 : 1.0f)
                 * ((inc2 ? cb2 : 1.0f) * (inc3 ? cb3 : 1.0f));

        float ea  = __expf(za * mlt);
        float eb  = __expf(zb * mlt);
        float gva = fmaf(fast_rcp(1.0f + ea), ga, gb);
        float gvb = fmaf(fast_rcp(1.0f + eb), ga, gb);

        float fa = dpp_f<QP_BCAST0>(gva), fb = dpp_f<QP_BCAST0>(gvb);
        float ia = dpp_f<QP_BCAST1>(gva), ib = dpp_f<QP_BCAST1>(gvb);
        float g_a = dpp_f<QP_BCAST2>(gva), g_b = dpp_f<QP_BCAST2>(gvb);
        float oa = dpp_f<QP_BCAST3>(gva), ob = dpp_f<QP_BCAST3>(gvb);

        cxa = fmaf(fa, cxa, ia * g_a);
        cxb = fmaf(fb, cxb, ib * g_b);
        // tanh(cx) inline so the two exp/rcp chains interleave
        float ta = fmaf(-2.0f, fast_rcp(1.0f + __expf(2.0f * cxa)), 1.0f);
        float tb = fmaf(-2.0f, fast_rcp(1.0f + __expf(2.0f * cxb)), 1.0f);
        hxa = oa * ta;
        hxb = ob * tb;
    };

    for (int t = 0; t < NPATCH; t += 7) {
        step(r0, t + 7);
        step(r1, t + 8);
        step(r2, t + 9);
        step(r3, t + 10);
        step(r4, t + 11);
        step(r5, t + 12);
        step(r6, t + 13);   // pad rows 196..203 exist, loaded but never decoded
    }

    // batch-sum of final h: both samples, then across the 4 row-groups of
    // the wave, then one atomic per (wave, u) from k==0 lanes of row 0.
    float v = hxa + hxb;
    v += __shfl_xor(v, 16, 64);
    v += __shfl_xor(v, 32, 64);
    if ((tid & 63) < 16 && k == 0) atomicAdd(sums + u, v);
}

// ---------------------------------------------------------------------------
// Kernel 3: out[b] = prod_j cos(w_j) * prod_j cos(x[b][j]), w = sums/B
// ---------------------------------------------------------------------------
__global__ __launch_bounds__(256) void final_kernel(const float* __restrict__ x,
                                                    const float* __restrict__ sums,
                                                    float* __restrict__ out,
                                                    int B, float invB)
{
    int b = blockIdx.x * blockDim.x + threadIdx.x;
    if (b >= B) return;
    float P = cosf(sums[0] * invB) * cosf(sums[1] * invB) *
              cosf(sums[2] * invB) * cosf(sums[3] * invB);
    const float4 xi = *(const float4*)(x + (size_t)b * 784);
    out[b] = P * cosf(xi.x) * cosf(xi.y) * cosf(xi.z) * cosf(xi.w);
}

extern "C" void kernel_launch(void* const* d_in, const int* in_sizes, int n_in,
                              void* d_out, int out_size, void* d_ws, size_t ws_size,
                              hipStream_t stream)
{
    const float* x      = (const float*)d_in[0];
    const float* rl     = (const float*)d_in[1];
    const float* lin_W  = (const float*)d_in[2];
    const float* lin_b  = (const float*)d_in[3];
    const float* qtheta = (const float*)d_in[4];
    float* out = (float*)d_out;
    int B = in_sizes[0] / 784;

    float*    sums  = (float*)d_ws;                      // 4 floats
    ushort_t* qfeat = (ushort_t*)((char*)d_ws + 256);    // [QROWS][B][4] bf16

    hipMemsetAsync(sums, 0, 4 * sizeof(float), stream);

    quanv_kernel<<<B / SPB, 256, 0, stream>>>(x, rl, qfeat, B);

    // (B/2 pairs) * 16 lanes = B*8 threads
    lstm_kernel<<<(B * 8) / 256, 256, 0, stream>>>(qfeat, lin_W, lin_b, qtheta, sums, B);

    final_kernel<<<(B + 255) / 256, 256, 0, stream>>>(x, sums, out, B, 1.0f / (float)B);
}